// Round 5
// baseline (678.867 us; speedup 1.0000x reference)
//
#include <hip/hip_runtime.h>
#include <hip/hip_bf16.h>

// Problem constants
constexpr int Bn  = 128;   // batch
constexpr int Ln  = 200;   // sentences
constexpr int D2n = 1024;  // 2*SH
constexpr int G3n = 1536;  // 3*EH
constexpr int Tn  = 3;
constexpr int Nn  = 512;   // A (attention dim) == d_proj cols
constexpr int Kn  = 1024;  // d_proj K

typedef unsigned short ushort;
typedef float f32x4 __attribute__((ext_vector_type(4)));
typedef __bf16 bf16x8 __attribute__((ext_vector_type(8)));

__device__ __forceinline__ ushort f2bf(float f) {   // RNE float->bf16
  unsigned u = __float_as_uint(f);
  unsigned r = (u + 0x7fffu + ((u >> 16) & 1u)) >> 16;
  return (ushort)r;
}
__device__ __forceinline__ float bf2f(ushort h) {
  return __uint_as_float(((unsigned)h) << 16);
}
__device__ __forceinline__ float fast_tanh(float x) {
  float ax = __builtin_fabsf(x);
  float e  = __expf(-2.f * ax);
  float t  = (1.f - e) / (1.f + e);
  return __builtin_copysignf(t, x);
}

// ---------------------------------------------------------------------------
// split W (fp32, N elements) into hi/lo bf16 (RNE, done once for wd)
__global__ void k_splitW(const float* __restrict__ W, ushort* __restrict__ hi,
                         ushort* __restrict__ lo) {
  int i = blockIdx.x * 256 + threadIdx.x;        // element/4
  float4 v = ((const float4*)W)[i];
  ushort4 h, l;
  h.x = f2bf(v.x); l.x = f2bf(v.x - bf2f(h.x));
  h.y = f2bf(v.y); l.y = f2bf(v.y - bf2f(h.y));
  h.z = f2bf(v.z); l.z = f2bf(v.z - bf2f(h.z));
  h.w = f2bf(v.w); l.w = f2bf(v.w - bf2f(h.w));
  ((ushort4*)hi)[i] = h;
  ((ushort4*)lo)[i] = l;
}

// ---------------------------------------------------------------------------
// small GEMM: out[b,j] = act(bias[j] + sum_k in[b,k] * W[j,k])
// in rows at in_stride (supports strided view into sent). 8 batches/block,
// 2 rows/thread. grid (J/64, B/8), block 256.
template<int K, int ACT>
__launch_bounds__(256)
__global__ void k_small_gemm(const float* __restrict__ in, long in_stride,
                             const float* __restrict__ W,
                             const float* __restrict__ bias, float* __restrict__ out, int J) {
  __shared__ float s[8 * K];
  const int b0 = blockIdx.y * 8;
  const int j  = blockIdx.x * 64 + (threadIdx.x & 63);
  const int bg = (threadIdx.x >> 6) * 2;         // 0,2,4,6

  #pragma unroll
  for (int r = 0; r < 8; ++r) {
    const float4* src = (const float4*)(in + (size_t)(b0 + r) * in_stride);
    float4* dst = (float4*)(s + r * K);
    for (int idx = threadIdx.x; idx < K / 4; idx += 256) dst[idx] = src[idx];
  }
  __syncthreads();

  const float4* w4 = (const float4*)(W + (size_t)j * K);
  const float4* r0 = (const float4*)(s + (size_t)(bg + 0) * K);
  const float4* r1 = (const float4*)(s + (size_t)(bg + 1) * K);

  float a00 = 0.f, a01 = 0.f, a10 = 0.f, a11 = 0.f;
  #pragma unroll 4
  for (int k4 = 0; k4 < K / 4; k4 += 2) {
    float4 w0 = w4[k4], w1 = w4[k4 + 1];
    float4 x;
    x = r0[k4];     a00 += w0.x*x.x + w0.y*x.y + w0.z*x.z + w0.w*x.w;
    x = r0[k4 + 1]; a01 += w1.x*x.x + w1.y*x.y + w1.z*x.z + w1.w*x.w;
    x = r1[k4];     a10 += w0.x*x.x + w0.y*x.y + w0.z*x.z + w0.w*x.w;
    x = r1[k4 + 1]; a11 += w1.x*x.x + w1.y*x.y + w1.z*x.z + w1.w*x.w;
  }
  float bb = bias[j], v;
  v = a00 + a01 + bb; if (ACT) v = tanhf(v); out[(size_t)(b0 + bg + 0) * J + j] = v;
  v = a10 + a11 + bb; if (ACT) v = tanhf(v); out[(size_t)(b0 + bg + 1) * J + j] = v;
}

// ---------------------------------------------------------------------------
// d_proj = sent @ wd^T + bd  via split-bf16 MFMA (3 mfma per tile, fp32 acc)
// M=25600 N=512 K=1024. Block 128x128, BK=32, 256 thr = 4 waves of 64x64.
constexpr int LDW = 36;   // padded LDS row (shorts): 72 B = 18 banks, odd-ish stride
__launch_bounds__(256)
__global__ void k_dproj_mfma(const float* __restrict__ A, const ushort* __restrict__ Whi,
                             const ushort* __restrict__ Wlo, const float* __restrict__ bias,
                             float* __restrict__ C) {
  __shared__ __align__(16) ushort Ah[128][LDW];
  __shared__ __align__(16) ushort Al[128][LDW];
  __shared__ __align__(16) ushort Bh[128][LDW];
  __shared__ __align__(16) ushort Bl[128][LDW];

  const int m0 = blockIdx.x * 128, n0 = blockIdx.y * 128;
  const int tid  = threadIdx.x;
  const int wave = tid >> 6, lane = tid & 63;
  const int wy = (wave >> 1) * 64, wx = (wave & 1) * 64;
  const int lm = lane & 15, lq = lane >> 4;      // tile row, quad

  const int sr   = tid >> 1;                     // staging row 0..127
  const int sk   = (tid & 1) * 16;               // staging k-offset 0/16

  f32x4 acc[4][4] = {};

  const float* Arow = A + (size_t)(m0 + sr) * Kn + sk;
  const ushort* Bhrow = Whi + (size_t)(n0 + sr) * Kn + sk;
  const ushort* Blrow = Wlo + (size_t)(n0 + sr) * Kn + sk;

  for (int k0 = 0; k0 < Kn; k0 += 32) {
    // ---- stage A: fp32 -> hi/lo bf16 by truncation (cheap, err ~2^-16 rel)
    #pragma unroll
    for (int i = 0; i < 4; ++i) {
      float4 v = *(const float4*)(Arow + k0 + i * 4);
      ushort4 h, l;
      unsigned u;
      u = __float_as_uint(v.x); h.x = (ushort)(u >> 16);
      l.x = (ushort)(__float_as_uint(v.x - __uint_as_float(u & 0xffff0000u)) >> 16);
      u = __float_as_uint(v.y); h.y = (ushort)(u >> 16);
      l.y = (ushort)(__float_as_uint(v.y - __uint_as_float(u & 0xffff0000u)) >> 16);
      u = __float_as_uint(v.z); h.z = (ushort)(u >> 16);
      l.z = (ushort)(__float_as_uint(v.z - __uint_as_float(u & 0xffff0000u)) >> 16);
      u = __float_as_uint(v.w); h.w = (ushort)(u >> 16);
      l.w = (ushort)(__float_as_uint(v.w - __uint_as_float(u & 0xffff0000u)) >> 16);
      *(ushort4*)&Ah[sr][sk + i * 4] = h;
      *(ushort4*)&Al[sr][sk + i * 4] = l;
    }
    // ---- stage B (pre-split bf16)
    #pragma unroll
    for (int i = 0; i < 2; ++i) {
      *(int4*)&Bh[sr][sk + i * 8] = *(const int4*)(Bhrow + k0 + i * 8);
      *(int4*)&Bl[sr][sk + i * 8] = *(const int4*)(Blrow + k0 + i * 8);
    }
    __syncthreads();

    bf16x8 ah[4], al[4], bh[4], bl[4];
    #pragma unroll
    for (int mi = 0; mi < 4; ++mi) {
      ah[mi] = *(const bf16x8*)&Ah[wy + mi * 16 + lm][lq * 8];
      al[mi] = *(const bf16x8*)&Al[wy + mi * 16 + lm][lq * 8];
    }
    #pragma unroll
    for (int ni = 0; ni < 4; ++ni) {
      bh[ni] = *(const bf16x8*)&Bh[wx + ni * 16 + lm][lq * 8];
      bl[ni] = *(const bf16x8*)&Bl[wx + ni * 16 + lm][lq * 8];
    }
    #pragma unroll
    for (int mi = 0; mi < 4; ++mi)
      #pragma unroll
      for (int ni = 0; ni < 4; ++ni) {
        acc[mi][ni] = __builtin_amdgcn_mfma_f32_16x16x32_bf16(ah[mi], bh[ni], acc[mi][ni], 0, 0, 0);
        acc[mi][ni] = __builtin_amdgcn_mfma_f32_16x16x32_bf16(ah[mi], bl[ni], acc[mi][ni], 0, 0, 0);
        acc[mi][ni] = __builtin_amdgcn_mfma_f32_16x16x32_bf16(al[mi], bh[ni], acc[mi][ni], 0, 0, 0);
      }
    __syncthreads();
  }

  // epilogue: D[row=quad*4+r][col=lane&15] per 16x16 tile
  #pragma unroll
  for (int ni = 0; ni < 4; ++ni) {
    int col = n0 + wx + ni * 16 + lm;
    float bb = bias[col];
    #pragma unroll
    for (int mi = 0; mi < 4; ++mi) {
      int rbase = m0 + wy + mi * 16 + lq * 4;
      #pragma unroll
      for (int r = 0; r < 4; ++r)
        C[(size_t)(rbase + r) * Nn + col] = acc[mi][ni][r] + bb;
    }
  }
}

// ---------------------------------------------------------------------------
// GRU pointwise: h = (1-z)*n + z*h
__global__ void k_gru_pw(const float* __restrict__ gx, const float* __restrict__ gh,
                         float* __restrict__ h) {
  int i = blockIdx.x * 256 + threadIdx.x;        // 65536
  int b = i >> 9, j = i & 511;
  const float* gxb = gx + (size_t)b * G3n;
  const float* ghb = gh + (size_t)b * G3n;
  float rg = 1.f / (1.f + expf(-(gxb[j] + ghb[j])));
  float zg = 1.f / (1.f + expf(-(gxb[512 + j] + ghb[512 + j])));
  float ng = tanhf(gxb[1024 + j] + rg * ghb[1024 + j]);
  h[i] = (1.f - zg) * ng + zg * h[i];
}

// ---------------------------------------------------------------------------
// score[b,l] = sum_a tanh(q[b,a] + dproj[b*L+l, a]) * ws[a] + bs ; apply mask
__launch_bounds__(256)
__global__ void k_score(const float* __restrict__ dproj, const float* __restrict__ q,
                        const float* __restrict__ wsv, const float* __restrict__ bsv,
                        const int* __restrict__ mask, float* __restrict__ scoresf,
                        float* __restrict__ outScores, int t) {
  int w = blockIdx.x * 4 + (threadIdx.x >> 6);   // 0..25599
  int lane = threadIdx.x & 63;
  int b = w / Ln, l = w % Ln;
  const float4* dp4 = (const float4*)(dproj + (size_t)w * Nn);
  const float4* q4  = (const float4*)(q + (size_t)b * Nn);
  const float4* ws4 = (const float4*)wsv;

  float sum = 0.f;
  #pragma unroll
  for (int i = 0; i < 2; ++i) {
    int idx = lane + i * 64;                     // 128 float4 per row
    float4 d = dp4[idx], qq = q4[idx], wv = ws4[idx];
    sum += fast_tanh(qq.x + d.x) * wv.x + fast_tanh(qq.y + d.y) * wv.y
         + fast_tanh(qq.z + d.z) * wv.z + fast_tanh(qq.w + d.w) * wv.w;
  }
  #pragma unroll
  for (int off = 32; off > 0; off >>= 1) sum += __shfl_xor(sum, off, 64);

  if (lane == 0) {
    float v = sum + bsv[0];
    if (mask[w]) v = -1000000.0f;
    scoresf[w] = v;
    outScores[(size_t)b * (Tn * Ln) + t * Ln + l] = v;
  }
}

// ---------------------------------------------------------------------------
// per-batch argmax (first-index tie-break), update mask, gather selected row
__launch_bounds__(256)
__global__ void k_argmax(const float* __restrict__ scoresf, const float* __restrict__ sent,
                         float* __restrict__ s_row, int* __restrict__ mask,
                         float* __restrict__ outSel, int t) {
  int b = blockIdx.x;
  __shared__ int s_idx;
  int tid = threadIdx.x;
  if (tid < 64) {
    const float* sc = scoresf + (size_t)b * Ln;
    float best = -3.0e38f; int bi = 0;
    for (int l = tid; l < Ln; l += 64) {
      float v = sc[l];
      if (v > best) { best = v; bi = l; }        // increasing l: strict > keeps first
    }
    #pragma unroll
    for (int off = 32; off > 0; off >>= 1) {
      float ov = __shfl_down(best, off, 64);
      int   oi = __shfl_down(bi,   off, 64);
      if (ov > best || (ov == best && oi < bi)) { best = ov; bi = oi; }
    }
    if (tid == 0) s_idx = bi;
  }
  __syncthreads();
  int idx = s_idx;
  const float* src = sent + ((size_t)b * Ln + idx) * D2n;
  float* dstp = s_row + (size_t)b * D2n;
  int k = tid * 4;                               // 256 threads x 4 = 1024
  *(float4*)(dstp + k) = *(const float4*)(src + k);
  if (tid == 0) {
    mask[b * Ln + idx] = 1;
    outSel[(size_t)b * Tn + t] = (float)idx;
  }
}

// ---------------------------------------------------------------------------
extern "C" void kernel_launch(void* const* d_in, const int* in_sizes, int n_in,
                              void* d_out, int out_size, void* d_ws, size_t ws_size,
                              hipStream_t stream) {
  const float* sent = (const float*)d_in[0];
  const float* h0_w = (const float*)d_in[1];
  const float* h0_b = (const float*)d_in[2];
  const float* w_ih = (const float*)d_in[3];
  const float* w_hh = (const float*)d_in[4];
  const float* b_ih = (const float*)d_in[5];
  const float* b_hh = (const float*)d_in[6];
  const float* wq   = (const float*)d_in[7];
  const float* bq   = (const float*)d_in[8];
  const float* wd   = (const float*)d_in[9];
  const float* bd   = (const float*)d_in[10];
  const float* wsv  = (const float*)d_in[11];
  const float* bsv  = (const float*)d_in[12];

  float* wsf     = (float*)d_ws;
  float* d_proj  = wsf;                       // 25600*512 = 13107200
  float* s_row   = d_proj + 13107200;         // 128*1024
  float* h       = s_row + 131072;            // 128*512
  float* gx      = h + 65536;                 // 128*1536
  float* gh      = gx + 196608;               // 128*1536
  float* lastb   = gh + 196608;               // (unused slot)
  float* q       = lastb + 65536;             // 128*512
  float* scoresf = q + 65536;                 // 128*200
  int*   mask    = (int*)(scoresf + 25600);   // 128*200 ints
  ushort* Whi    = (ushort*)(mask + 25600);   // 512*1024 shorts
  ushort* Wlo    = Whi + 524288;              // 512*1024 shorts

  float* outScores = (float*)d_out;                       // (B, T, L) fp32
  float* outSel    = outScores + (size_t)Bn * Tn * Ln;    // (B, T) fp32

  hipMemsetAsync(s_row, 0, 131072 * sizeof(float), stream);       // s_prev(t=0) = 0
  hipMemsetAsync(mask, 0, 25600 * sizeof(int), stream);

  // h0 = tanh(last_back @ h0_w^T + h0_b): read sent[:,0,512:] via stride
  k_small_gemm<512, 1><<<dim3(8, 16), 256, 0, stream>>>(sent + 512, (long)Ln * D2n,
                                                        h0_w, h0_b, h, 512);
  k_splitW<<<512, 256, 0, stream>>>(wd, Whi, Wlo);        // 512*1024/4 = 131072 float4
  k_dproj_mfma<<<dim3(200, 4), 256, 0, stream>>>(sent, Whi, Wlo, bd, d_proj);

  for (int t = 0; t < Tn; ++t) {
    k_small_gemm<1024, 0><<<dim3(24, 16), 256, 0, stream>>>(s_row, 1024, w_ih, b_ih, gx, G3n);
    k_small_gemm<512, 0><<<dim3(24, 16), 256, 0, stream>>>(h, 512, w_hh, b_hh, gh, G3n);
    k_gru_pw<<<256, 256, 0, stream>>>(gx, gh, h);
    k_small_gemm<512, 0><<<dim3(8, 16), 256, 0, stream>>>(h, 512, wq, bq, q, 512);
    k_score<<<6400, 256, 0, stream>>>(d_proj, q, wsv, bsv, mask, scoresf, outScores, t);
    k_argmax<<<128, 256, 0, stream>>>(scoresf, sent, s_row, mask, outSel, t);
  }
}